// Round 10
// baseline (750.797 us; speedup 1.0000x reference)
//
#include <hip/hip_runtime.h>
#include <hip/hip_bf16.h>
#include <cstdint>

typedef unsigned short u16;
typedef __attribute__((ext_vector_type(8))) _Float16 f16x8;
typedef __attribute__((ext_vector_type(4))) float f32x4;
typedef __attribute__((ext_vector_type(8))) unsigned short u16x8;

typedef const __attribute__((address_space(1))) void* gas1p;
typedef __attribute__((address_space(3))) void* las3p;
typedef const __attribute__((address_space(3))) u16* lc16p;

__device__ __forceinline__ void gld_lds16(const void* g, void* l) {
    __builtin_amdgcn_global_load_lds((gas1p)g, (las3p)l, 16, 0, 0);
}

// clobber-free asm ds_read_b128; RAW/WAR enforced by the explicit counted waits.
__device__ __forceinline__ f16x8 dsr128(const u16* p) {
    f16x8 r;
    asm volatile("ds_read_b128 %0, %1" : "=v"(r) : "v"((lc16p)p));
    return r;
}

__device__ __forceinline__ u16 f2h(float f) {
    _Float16 h = (_Float16)f;
    return __builtin_bit_cast(u16, h);
}

// ---------------- prep: x fp32 -> fp16 ----------------
__global__ void cvt_x_kernel(const float4* __restrict__ x, u16* __restrict__ xb) {
    size_t i = (size_t)blockIdx.x * blockDim.x + threadIdx.x;
    float4 a = x[2 * i];
    float4 b = x[2 * i + 1];
    u16x8 o;
    o[0] = f2h(a.x); o[1] = f2h(a.y); o[2] = f2h(a.z); o[3] = f2h(a.w);
    o[4] = f2h(b.x); o[5] = f2h(b.y); o[6] = f2h(b.z); o[7] = f2h(b.w);
    *(u16x8*)&xb[i * 8] = o;
}

// ---------------- prep: weight norm, all 5 layers in 2 launches ----------------
struct WnDesc {
    const float* v; const float* g; u16* wT; float* partial;
    int K; int N; int blk0;
};
struct WnPack { WnDesc d[5]; int nlayer; };

__global__ void wn_partial_all(WnPack p) {
    int b = blockIdx.x;
    int l = 0;
    while (l + 1 < p.nlayer && b >= p.d[l + 1].blk0) l++;
    const WnDesc& d = p.d[l];
    int lb = b - d.blk0;
    int nbx = d.N >> 6;
    int bx = lb % nbx, seg = lb / nbx;

    int lane = threadIdx.x & 63;
    int tr = threadIdx.x >> 6;
    int n = bx * 64 + lane;
    int kseg = d.K >> 3;
    int kbeg = seg * kseg;
    float s = 0.f;
    for (int k = kbeg + tr; k < kbeg + kseg; k += 4) {
        float x = d.v[(size_t)k * d.N + n];
        s += x * x;
    }
    __shared__ float red[4][64];
    red[tr][lane] = s;
    __syncthreads();
    if (tr == 0)
        d.partial[seg * d.N + n] = red[0][lane] + red[1][lane] + red[2][lane] + red[3][lane];
}

__global__ void wn_write_all(WnPack p) {
    int b = blockIdx.x;
    int l = 0;
    while (l + 1 < p.nlayer && b >= p.d[l + 1].blk0) l++;
    const WnDesc& d = p.d[l];
    int lb = b - d.blk0;
    int nbx = d.N >> 6;
    int bx = lb % nbx, seg = lb / nbx;

    int lane = threadIdx.x & 63;
    int tr = threadIdx.x >> 6;
    int n = bx * 64 + lane;
    float s = 0.f;
#pragma unroll
    for (int i = 0; i < 8; i++) s += d.partial[i * d.N + n];
    float sc = d.g[n] / sqrtf(s);

    int kseg = d.K >> 3;
    int kbeg = seg * kseg;
    for (int k = kbeg + tr; k < kbeg + kseg; k += 4)
        d.wT[(size_t)n * d.K + k] = f2h(d.v[(size_t)k * d.N + n] * sc);
}

// ---------------- persistent GEMM: 256 blocks, stitched G-tile ring ------------
// Block = one 256-row M-panel; iterates all NTN n-tiles in ONE continuous ring
// of G = NTK*NTN K-steps (A k-offset wraps, B base jumps panels at seams).
// Per step g (tile buffers cur=g&1): stages target g+2 (A0@P1, B0@P2, A1,B1@P4).
// Counted drains BEFORE barriers (cross-wave safe: wait -> barrier -> read):
//   W2 = end-P2 vmcnt(4): forces {A0,B0}(g+1)   [read at P3/P4]
//   W4 = end-P4 vmcnt(4): forces {A1,B1}(g+1)   [read at P1/P2 next step]
// Tail: g=G-2 uses vmcnt(2)/vmcnt(0); g=G-1 peeled, no waits needed.
// Seam (g%NTK==NTK-1): epilogue inside ring; its stores only over-strengthen
// the next W2 (queue-simulated; invariant re-established by W4(g+2)).
template<int N, int K, bool ACT, bool OUTF32>
__global__ __launch_bounds__(512, 2) void gemm_persist(
    const u16* __restrict__ A, const u16* __restrict__ Bt,
    u16* __restrict__ Ch, float* __restrict__ Cf)
{
    constexpr int M = 65536;
    constexpr int NTK = K / 64;
    constexpr int LOGK = (NTK == 8) ? 3 : 4;
    constexpr int NTN = N / 256;
    constexpr int G = NTK * NTN;
    constexpr int NWG = M / 256;            // 256 persistent blocks

    __shared__ u16 sA[2][256 * 64];
    __shared__ u16 sB[2][2 * 128 * 64];

    const int bid = blockIdx.x;
    const int wk = (bid & 7) * (NWG >> 3) + (bid >> 3);   // bijective: 256%8==0
    const long m0 = (long)wk * 256;

    const int tid = threadIdx.x;
    const int lane = tid & 63;
    const int wid = tid >> 6;
    const int wm = (wid >> 2) * 128;
    const int wn = (wid & 3) * 64;

    const int r8 = tid >> 3;
    const int gcol = ((tid & 7) ^ (r8 & 7)) * 8;
    const u16* Abase = A + (m0 + r8) * (size_t)K + gcol;
    const u16* Bbase = Bt + (size_t)((r8 >> 5) * 64 + (r8 & 31)) * K + gcol;
    const int dst8 = tid * 8;

    auto aoff = [&](int gs) { return (size_t)(gs & (NTK - 1)) * 64; };
    auto boff = [&](int gs) {
        return (size_t)(gs >> LOGK) * ((size_t)256 * K) + (size_t)(gs & (NTK - 1)) * 64;
    };
    auto stA0 = [&](int buf, int gs) {
        gld_lds16(Abase + aoff(gs), &sA[buf][dst8]);
        gld_lds16(Abase + (size_t)128 * K + aoff(gs), &sA[buf][2 * 4096 + dst8]);
    };
    auto stA1 = [&](int buf, int gs) {
        gld_lds16(Abase + (size_t)64 * K + aoff(gs), &sA[buf][1 * 4096 + dst8]);
        gld_lds16(Abase + (size_t)192 * K + aoff(gs), &sA[buf][3 * 4096 + dst8]);
    };
    auto stB0 = [&](int buf, int gs) {
        gld_lds16(Bbase + boff(gs), &sB[buf][dst8]);
        gld_lds16(Bbase + (size_t)128 * K + boff(gs), &sB[buf][4096 + dst8]);
    };
    auto stB1 = [&](int buf, int gs) {
        gld_lds16(Bbase + (size_t)32 * K + boff(gs), &sB[buf][8192 + dst8]);
        gld_lds16(Bbase + (size_t)160 * K + boff(gs), &sB[buf][8192 + 4096 + dst8]);
    };

    const int rbase = lane & 15;
    const int co0 = ((lane >> 4) ^ (lane & 7)) * 8;
    const int arow0 = (wm + rbase) * 64 + co0;
    const int brow0 = ((wn >> 6) * 32 + rbase) * 64 + co0;

    f32x4 acc[8][4] = {};
    f16x8 rA0[4][2], rA1[4][2], rB0[2][2], rB1[2][2];

    auto dsrA = [&](f16x8 (&r)[4][2], int buf, int qm) {
#pragma unroll
        for (int i = 0; i < 4; i++) {
            int base = arow0 + (qm * 64 + i * 16) * 64;
            r[i][0] = dsr128(&sA[buf][base]);
            r[i][1] = dsr128(&sA[buf][base ^ 32]);
        }
    };
    auto dsrB = [&](f16x8 (&r)[2][2], int buf, int qn) {
#pragma unroll
        for (int j2 = 0; j2 < 2; j2++) {
            int base = brow0 + qn * 8192 + j2 * 1024;
            r[j2][0] = dsr128(&sB[buf][base]);
            r[j2][1] = dsr128(&sB[buf][base ^ 32]);
        }
    };
    auto mm = [&](f16x8 (&ra)[4][2], f16x8 (&rb)[2][2], int qm, int qn) {
        __builtin_amdgcn_s_setprio(1);
#pragma unroll
        for (int kk = 0; kk < 2; kk++)
#pragma unroll
            for (int i = 0; i < 4; i++)
#pragma unroll
                for (int j2 = 0; j2 < 2; j2++)
                    acc[qm * 4 + i][qn * 2 + j2] = __builtin_amdgcn_mfma_f32_16x16x32_f16(
                        ra[i][kk], rb[j2][kk], acc[qm * 4 + i][qn * 2 + j2], 0, 0, 0);
        __builtin_amdgcn_s_setprio(0);
    };
    auto BAR = [&]() { __builtin_amdgcn_s_barrier(); };
#define LGKM(n) { asm volatile("s_waitcnt lgkmcnt(" #n ")"); __builtin_amdgcn_sched_barrier(0); }
#define VMC(n)  { asm volatile("s_waitcnt vmcnt(" #n ")");  __builtin_amdgcn_sched_barrier(0); }

    auto epilogue = [&](int tn) {
        const long crow0 = m0 + wm + ((lane >> 4) << 2);
        const int ccol0 = tn * 256 + wn + (lane & 15);
#pragma unroll
        for (int fi = 0; fi < 8; fi++) {
#pragma unroll
            for (int r = 0; r < 4; r++) {
                const size_t rowoff = (size_t)(crow0 + fi * 16 + r) * N;
#pragma unroll
                for (int fj = 0; fj < 4; fj++) {
                    float v = acc[fi][fj][r];
                    if (ACT) v = fmaxf(v, 0.f) + __logf(1.f + __expf(-fabsf(v)));
                    if (OUTF32) Cf[rowoff + ccol0 + fj * 16] = v;
                    else        Ch[rowoff + ccol0 + fj * 16] = f2h(v);
                }
            }
        }
#pragma unroll
        for (int i = 0; i < 8; i++)
#pragma unroll
            for (int j = 0; j < 4; j++)
                acc[i][j] = (f32x4){0.f, 0.f, 0.f, 0.f};
    };

    // ---- prologue: stage tiles 0,1 (8 half-stages); force tile0; pre-read ----
    stA0(0, 0); stB0(0, 0); stA1(0, 0); stB1(0, 0);
    stA0(1, 1); stB0(1, 1); stA1(1, 1); stB1(1, 1);
    VMC(4);                      // forces tile0 fully, leaves tile1's 4
    BAR();
    dsrA(rA0, 0, 0); dsrB(rB0, 0, 0);
    LGKM(0);
    BAR();

    // ---- stitched ring: g = 0 .. G-2 uniform ----
    for (int g = 0; g < G - 1; g++) {
        const int cur = g & 1, nxt = cur ^ 1;
        const bool st = (g < G - 2);
        // P1
        dsrB(rB1, cur, 1);
        if (st) stA0(cur, g + 2);
        BAR(); LGKM(4);
        mm(rA0, rB0, 0, 0);
        BAR();
        // P2
        dsrA(rA1, cur, 1);
        if (st) stB0(cur, g + 2);
        BAR(); LGKM(8);
        mm(rA0, rB1, 0, 1);
        if (st) { VMC(4); } else { VMC(2); }   // forces {A0,B0}(g+1)
        BAR();
        // P3
        dsrA(rA0, nxt, 0);
        BAR(); LGKM(8);
        mm(rA1, rB0, 1, 0);
        BAR();
        // P4
        dsrB(rB0, nxt, 0);
        if (st) { stA1(cur, g + 2); stB1(cur, g + 2); }
        BAR();
        mm(rA1, rB1, 1, 1);
        if (st) { VMC(4); } else { VMC(0); }   // forces {A1,B1}(g+1)
        BAR();
        // n-tile seam: epilogue inside the ring (prefetches stay in flight)
        if ((g & (NTK - 1)) == NTK - 1) epilogue(g >> LOGK);
    }
    // ---- peeled g = G-1: everything already forced; no barriers needed ----
    {
        const int cur = (G - 1) & 1;
        dsrB(rB1, cur, 1);
        LGKM(4);
        mm(rA0, rB0, 0, 0);
        dsrA(rA1, cur, 1);
        LGKM(8);
        mm(rA0, rB1, 0, 1);
        LGKM(0);
        mm(rA1, rB0, 1, 0);
        mm(rA1, rB1, 1, 1);
        epilogue(NTN - 1);
    }
#undef LGKM
#undef VMC
}

// ---------------- launch ----------------
extern "C" void kernel_launch(void* const* d_in, const int* in_sizes, int n_in,
                              void* d_out, int out_size, void* d_ws, size_t ws_size,
                              hipStream_t stream) {
    const float* x  = (const float*)d_in[0];
    const float* v1 = (const float*)d_in[1];
    const float* g1 = (const float*)d_in[2];
    const float* v2 = (const float*)d_in[3];
    const float* g2 = (const float*)d_in[4];
    const float* v3 = (const float*)d_in[5];
    const float* g3 = (const float*)d_in[6];
    const float* v4 = (const float*)d_in[7];
    const float* g4 = (const float*)d_in[8];
    const float* v5 = (const float*)d_in[9];
    const float* g5 = (const float*)d_in[10];
    float* out = (float*)d_out;

    const int M = 65536;
    char* ws = (char*)d_ws;
    u16* bufA = (u16*)(ws);                          // 128 MB
    u16* bufB = (u16*)(ws + 0x8000000ULL);           // 128 MB
    u16* w1T  = (u16*)(ws + 0x10000000ULL);
    u16* w2T  = w1T + 1024 * 512;
    u16* w3T  = w2T + 1024 * 1024;
    u16* w4T  = w3T + 1024 * 1024;
    u16* w5T  = w4T + 1024 * 1024;
    float* part = (float*)(ws + 0x10800000ULL);      // 5 x 8 x 1024 f32

    cvt_x_kernel<<<(M * 512) / (256 * 8), 256, 0, stream>>>((const float4*)x, bufB);

    WnPack pk;
    int cum = 0;
    auto mk = [&](int i, const float* v, const float* g, u16* wT, int K, int N) {
        pk.d[i] = WnDesc{v, g, wT, part + i * 8 * 1024, K, N, cum};
        cum += (N / 64) * 8;
    };
    mk(0, v1, g1, w1T, 512, 1024);
    mk(1, v2, g2, w2T, 1024, 1024);
    mk(2, v3, g3, w3T, 1024, 1024);
    mk(3, v4, g4, w4T, 1024, 1024);
    mk(4, v5, g5, w5T, 1024, 512);
    pk.nlayer = 5;

    wn_partial_all<<<cum, 256, 0, stream>>>(pk);
    wn_write_all<<<cum, 256, 0, stream>>>(pk);

    gemm_persist<1024, 512,  true,  false><<<256, 512, 0, stream>>>(bufB, w1T, bufA, nullptr);
    gemm_persist<1024, 1024, true,  false><<<256, 512, 0, stream>>>(bufA, w2T, bufB, nullptr);
    gemm_persist<1024, 1024, true,  false><<<256, 512, 0, stream>>>(bufB, w3T, bufA, nullptr);
    gemm_persist<1024, 1024, true,  false><<<256, 512, 0, stream>>>(bufA, w4T, bufB, nullptr);
    gemm_persist<512,  1024, false, true ><<<256, 512, 0, stream>>>(bufB, w5T, nullptr, out);

    (void)in_sizes; (void)n_in; (void)out_size; (void)ws_size;
}